// Round 1
// baseline (889.576 us; speedup 1.0000x reference)
//
#include <hip/hip_runtime.h>
#include <math.h>

#define SEQ 576
#define DIM 192
#define INNER 384
#define NHEAD 96
#define HS 24
#define WSZ 24
#define GIN 1152

__device__ __forceinline__ float wave_reduce_sum(float v) {
  #pragma unroll
  for (int off = 32; off > 0; off >>= 1) v += __shfl_down(v, off);
  return __shfl(v, 0);
}

// 1) LayerNorm over DIM=192, one wave per row
__global__ __launch_bounds__(64) void k_ln(const float* __restrict__ x,
    const float* __restrict__ w, const float* __restrict__ b,
    float* __restrict__ xn) {
  int s = blockIdx.x, t = threadIdx.x;
  const float* xr = x + s * DIM;
  float a0 = xr[t], a1 = xr[t + 64], a2 = xr[t + 128];
  float mu = wave_reduce_sum(a0 + a1 + a2) * (1.0f / DIM);
  float d0 = a0 - mu, d1 = a1 - mu, d2 = a2 - mu;
  float var = wave_reduce_sum(d0 * d0 + d1 * d1 + d2 * d2) * (1.0f / DIM);
  float inv = rsqrtf(var + 1e-5f);
  float* o = xn + s * DIM;
  o[t]       = d0 * inv * w[t]       + b[t];
  o[t + 64]  = d1 * inv * w[t + 64]  + b[t + 64];
  o[t + 128] = d2 * inv * w[t + 128] + b[t + 128];
}

// 2) x_inner = xn @ up_w.T + up_b   [SEQ,768]
__global__ __launch_bounds__(256) void k_up(const float* __restrict__ xn,
    const float* __restrict__ w, const float* __restrict__ b,
    float* __restrict__ out) {
  int s = blockIdx.x, t = threadIdx.x;
  __shared__ float xr[DIM];
  if (t < DIM) xr[t] = xn[s * DIM + t];
  __syncthreads();
  for (int o = t; o < 2 * INNER; o += 256) {
    const float* wr = w + o * DIM;
    float acc = b[o];
    #pragma unroll 4
    for (int i = 0; i < DIM; ++i) acc += xr[i] * wr[i];
    out[s * (2 * INNER) + o] = acc;
  }
}

// 3) depthwise 3x3 conv over 24x24 grid on x_mlstm (= x_inner[:, :384]) + SiLU
__global__ __launch_bounds__(384) void k_conv(const float* __restrict__ xin,
    const float* __restrict__ cw, const float* __restrict__ cb,
    float* __restrict__ xa) {
  int s = blockIdx.x, c = threadIdx.x;
  int h = s / WSZ, w = s % WSZ;
  float acc = cb[c];
  #pragma unroll
  for (int kh = 0; kh < 3; ++kh) {
    int hh = h + kh - 1;
    if (hh < 0 || hh >= HS) continue;
    #pragma unroll
    for (int kw = 0; kw < 3; ++kw) {
      int ww = w + kw - 1;
      if (ww < 0 || ww >= WSZ) continue;
      acc += xin[(hh * WSZ + ww) * (2 * INNER) + c] * cw[c * 9 + kh * 3 + kw];
    }
  }
  float sig = 1.0f / (1.0f + __expf(-acc));
  xa[s * INNER + c] = acc * sig;
}

// 4) headwise q,k,v (per-head 4x4) -> gin [SEQ, 1152] = [q | k | v]
__global__ __launch_bounds__(384) void k_qkv(const float* __restrict__ xa,
    const float* __restrict__ xin,
    const float* __restrict__ qw, const float* __restrict__ qb,
    const float* __restrict__ kw, const float* __restrict__ kb,
    const float* __restrict__ vw, const float* __restrict__ vb,
    float* __restrict__ gin) {
  int s = blockIdx.x, t = threadIdx.x;
  int n = t >> 2, o = t & 3;
  __shared__ float xas[INNER], xms[INNER];
  xas[t] = xa[s * INNER + t];
  xms[t] = xin[s * (2 * INNER) + t];
  __syncthreads();
  const float* xah = xas + n * 4;
  const float* xmh = xms + n * 4;
  float q = qb[t], k = kb[t], v = vb[t];
  #pragma unroll
  for (int i = 0; i < 4; ++i) {
    float xq = xah[i], xm = xmh[i];
    q += xq * qw[n * 16 + o * 4 + i];
    k += xq * kw[n * 16 + o * 4 + i];
    v += xm * vw[n * 16 + o * 4 + i];
  }
  gin[s * GIN + t]               = q;
  gin[s * GIN + INNER + t]       = k;
  gin[s * GIN + 2 * INNER + t]   = v;
}

// 5) gates: ig[n][s], logf[n][s] = log_sigmoid(fg)  — block per head
__global__ __launch_bounds__(256) void k_gates(const float* __restrict__ gin,
    const float* __restrict__ igw, const float* __restrict__ igb,
    const float* __restrict__ fgw, const float* __restrict__ fgb,
    float* __restrict__ ig, float* __restrict__ logf) {
  int n = blockIdx.x, t = threadIdx.x;
  int wave = t >> 6, lane = t & 63;
  __shared__ float wi[GIN], wf[GIN];
  for (int j = t; j < GIN; j += 256) { wi[j] = igw[n * GIN + j]; wf[j] = fgw[n * GIN + j]; }
  __syncthreads();
  for (int s = wave; s < SEQ; s += 4) {
    const float* g = gin + s * GIN;
    float ai = 0.f, af = 0.f;
    for (int j = lane; j < GIN; j += 64) { float gv = g[j]; ai += gv * wi[j]; af += gv * wf[j]; }
    #pragma unroll
    for (int off = 32; off > 0; off >>= 1) { ai += __shfl_down(ai, off); af += __shfl_down(af, off); }
    if (lane == 0) {
      ig[n * SEQ + s] = ai + igb[n];
      float f = af + fgb[n];
      float ls = (f >= 0.f) ? -log1pf(expf(-f)) : (f - log1pf(expf(f)));
      logf[n * SEQ + s] = ls;
    }
  }
}

// 6) per-head inclusive cumsum of logf -> lfc (wave scan, 9 chunks of 64)
__global__ __launch_bounds__(64) void k_scan(const float* __restrict__ logf,
    float* __restrict__ lfc) {
  int n = blockIdx.x, t = threadIdx.x;
  float carry = 0.f;
  for (int c = 0; c < SEQ / 64; ++c) {
    int s = c * 64 + t;
    float v = logf[n * SEQ + s];
    #pragma unroll
    for (int off = 1; off < 64; off <<= 1) {
      float u = __shfl_up(v, off);
      if (t >= off) v += u;
    }
    v += carry;
    lfc[n * SEQ + s] = v;
    carry = __shfl(v, 63);
  }
}

// 7) mLSTM core + per-head groupnorm.  Block per head, thread per query row.
//    logD[s,t]-maxD[s] = e[t] - pm[s],  e[t]=ig[t]-lfc[t], pm = prefix-max(e)
__global__ __launch_bounds__(576) void k_mlstm(const float* __restrict__ gin,
    const float* __restrict__ ig_g, const float* __restrict__ lfc_g,
    const float* __restrict__ onw, float* __restrict__ hout) {
  int n = blockIdx.x, s = threadIdx.x;
  __shared__ float ks[SEQ][4], vs[SEQ][4], es[SEQ];
  __shared__ float bufA[SEQ], bufB[SEQ];
  const float* g = gin + s * GIN;
  #pragma unroll
  for (int i = 0; i < 4; ++i) {
    ks[s][i] = g[INNER + n * 4 + i] * 0.5f;   // k / sqrt(DH)
    vs[s][i] = g[2 * INNER + n * 4 + i];
  }
  float lfs = lfc_g[n * SEQ + s];
  float e = ig_g[n * SEQ + s] - lfs;
  es[s] = e;
  bufA[s] = e;
  float q0 = g[n * 4], q1 = g[n * 4 + 1], q2 = g[n * 4 + 2], q3 = g[n * 4 + 3];
  __syncthreads();
  // prefix max over es
  float* src = bufA; float* dst = bufB;
  for (int off = 1; off < SEQ; off <<= 1) {
    float v = src[s];
    if (s >= off) v = fmaxf(v, src[s - off]);
    dst[s] = v;
    __syncthreads();
    float* tmp = src; src = dst; dst = tmp;
  }
  float pm = src[s];                    // max_{t<=s} e[t];  maxD = lfs + pm
  float csum = 0.f, h0 = 0.f, h1 = 0.f, h2 = 0.f, h3 = 0.f;
  for (int tt = 0; tt <= s; ++tt) {
    float d = __expf(es[tt] - pm);
    float c = (q0 * ks[tt][0] + q1 * ks[tt][1] + q2 * ks[tt][2] + q3 * ks[tt][3]) * d;
    csum += c;
    h0 += c * vs[tt][0]; h1 += c * vs[tt][1]; h2 += c * vs[tt][2]; h3 += c * vs[tt][3];
  }
  float norm = fmaxf(fabsf(csum), __expf(-(lfs + pm))) + 1e-6f;
  float r = 1.0f / norm;
  h0 *= r; h1 *= r; h2 *= r; h3 *= r;
  float mu = (h0 + h1 + h2 + h3) * 0.25f;
  float d0 = h0 - mu, d1 = h1 - mu, d2 = h2 - mu, d3 = h3 - mu;
  float var = (d0 * d0 + d1 * d1 + d2 * d2 + d3 * d3) * 0.25f;
  float inv = rsqrtf(var + 1e-5f);
  float* ho = hout + s * INNER + n * 4;
  ho[0] = d0 * inv * onw[n * 4];
  ho[1] = d1 * inv * onw[n * 4 + 1];
  ho[2] = d2 * inv * onw[n * 4 + 2];
  ho[3] = d3 * inv * onw[n * 4 + 3];
}

// 8) h2 = (h + skip*xa) * silu(z);  out = h2 @ down_w.T + down_b
__global__ __launch_bounds__(192) void k_down(const float* __restrict__ hmat,
    const float* __restrict__ xa, const float* __restrict__ xin,
    const float* __restrict__ skip, const float* __restrict__ dw,
    const float* __restrict__ db, float* __restrict__ out) {
  int s = blockIdx.x, t = threadIdx.x;
  __shared__ float h2[INNER];
  for (int c = t; c < INNER; c += 192) {
    float z = xin[s * (2 * INNER) + INNER + c];
    float sil = z / (1.0f + __expf(-z));
    h2[c] = (hmat[s * INNER + c] + skip[c] * xa[s * INNER + c]) * sil;
  }
  __syncthreads();
  const float* wr = dw + t * INNER;
  float acc = db[t];
  #pragma unroll 4
  for (int c = 0; c < INNER; ++c) acc += h2[c] * wr[c];
  out[s * DIM + t] = acc;
}

extern "C" void kernel_launch(void* const* d_in, const int* in_sizes, int n_in,
                              void* d_out, int out_size, void* d_ws, size_t ws_size,
                              hipStream_t stream) {
  const float* x      = (const float*)d_in[0];
  const float* ln_w   = (const float*)d_in[2];
  const float* ln_b   = (const float*)d_in[3];
  const float* up_w   = (const float*)d_in[4];
  const float* up_b   = (const float*)d_in[5];
  const float* q_w    = (const float*)d_in[8];
  const float* q_b    = (const float*)d_in[9];
  const float* k_w    = (const float*)d_in[10];
  const float* k_b    = (const float*)d_in[11];
  const float* v_w    = (const float*)d_in[12];
  const float* v_b    = (const float*)d_in[13];
  const float* conv_w = (const float*)d_in[14];
  const float* conv_b = (const float*)d_in[15];
  const float* ig_w   = (const float*)d_in[16];
  const float* ig_b   = (const float*)d_in[17];
  const float* fg_w   = (const float*)d_in[18];
  const float* fg_b   = (const float*)d_in[19];
  const float* onorm_w= (const float*)d_in[20];
  const float* skip   = (const float*)d_in[21];
  const float* down_w = (const float*)d_in[22];
  const float* down_b = (const float*)d_in[23];
  float* out = (float*)d_out;

  float* ws     = (float*)d_ws;
  float* xn     = ws;                       // 576*192
  float* xinner = xn + SEQ * DIM;           // 576*768
  float* xa     = xinner + SEQ * 2 * INNER; // 576*384
  float* gin    = xa + SEQ * INNER;         // 576*1152
  float* ig     = gin + SEQ * GIN;          // 96*576
  float* logf   = ig + NHEAD * SEQ;         // 96*576
  float* lfc    = logf + NHEAD * SEQ;       // 96*576
  float* hbuf   = lfc + NHEAD * SEQ;        // 576*384

  k_ln   <<<SEQ, 64, 0, stream>>>(x, ln_w, ln_b, xn);
  k_up   <<<SEQ, 256, 0, stream>>>(xn, up_w, up_b, xinner);
  k_conv <<<SEQ, 384, 0, stream>>>(xinner, conv_w, conv_b, xa);
  k_qkv  <<<SEQ, 384, 0, stream>>>(xa, xinner, q_w, q_b, k_w, k_b, v_w, v_b, gin);
  k_gates<<<NHEAD, 256, 0, stream>>>(gin, ig_w, ig_b, fg_w, fg_b, ig, logf);
  k_scan <<<NHEAD, 64, 0, stream>>>(logf, lfc);
  k_mlstm<<<NHEAD, SEQ, 0, stream>>>(gin, ig, lfc, onorm_w, hbuf);
  k_down <<<SEQ, 192, 0, stream>>>(hbuf, xa, xinner, skip, down_w, down_b, out);
}

// Round 2
// 194.967 us; speedup vs baseline: 4.5627x; 4.5627x over previous
//
#include <hip/hip_runtime.h>
#include <math.h>

#define SEQ 576
#define DIM 192
#define INNER 384
#define NHEAD 96
#define HS 24
#define WSZ 24
#define GIN 1152

__device__ __forceinline__ float wave_reduce_sum(float v) {
  #pragma unroll
  for (int off = 32; off > 0; off >>= 1) v += __shfl_down(v, off);
  return __shfl(v, 0);
}

// 1) LayerNorm over DIM=192, one wave per row
__global__ __launch_bounds__(64) void k_ln(const float* __restrict__ x,
    const float* __restrict__ w, const float* __restrict__ b,
    float* __restrict__ xn) {
  int s = blockIdx.x, t = threadIdx.x;
  const float* xr = x + s * DIM;
  float a0 = xr[t], a1 = xr[t + 64], a2 = xr[t + 128];
  float mu = wave_reduce_sum(a0 + a1 + a2) * (1.0f / DIM);
  float d0 = a0 - mu, d1 = a1 - mu, d2 = a2 - mu;
  float var = wave_reduce_sum(d0 * d0 + d1 * d1 + d2 * d2) * (1.0f / DIM);
  float inv = rsqrtf(var + 1e-5f);
  float* o = xn + s * DIM;
  o[t]       = d0 * inv * w[t]       + b[t];
  o[t + 64]  = d1 * inv * w[t + 64]  + b[t + 64];
  o[t + 128] = d2 * inv * w[t + 128] + b[t + 128];
}

// 2) x_inner = xn @ up_w.T + up_b   [SEQ,768]
__global__ __launch_bounds__(256) void k_up(const float* __restrict__ xn,
    const float* __restrict__ w, const float* __restrict__ b,
    float* __restrict__ out) {
  int s = blockIdx.x, t = threadIdx.x;
  __shared__ float xr[DIM];
  if (t < DIM) xr[t] = xn[s * DIM + t];
  __syncthreads();
  for (int o = t; o < 2 * INNER; o += 256) {
    const float* wr = w + o * DIM;
    float acc = b[o];
    #pragma unroll 4
    for (int i = 0; i < DIM; ++i) acc += xr[i] * wr[i];
    out[s * (2 * INNER) + o] = acc;
  }
}

// 3) depthwise 3x3 conv over 24x24 grid on x_mlstm (= x_inner[:, :384]) + SiLU
__global__ __launch_bounds__(384) void k_conv(const float* __restrict__ xin,
    const float* __restrict__ cw, const float* __restrict__ cb,
    float* __restrict__ xa) {
  int s = blockIdx.x, c = threadIdx.x;
  int h = s / WSZ, w = s % WSZ;
  float acc = cb[c];
  #pragma unroll
  for (int kh = 0; kh < 3; ++kh) {
    int hh = h + kh - 1;
    if (hh < 0 || hh >= HS) continue;
    #pragma unroll
    for (int kw = 0; kw < 3; ++kw) {
      int ww = w + kw - 1;
      if (ww < 0 || ww >= WSZ) continue;
      acc += xin[(hh * WSZ + ww) * (2 * INNER) + c] * cw[c * 9 + kh * 3 + kw];
    }
  }
  float sig = 1.0f / (1.0f + __expf(-acc));
  xa[s * INNER + c] = acc * sig;
}

// 4) headwise q,k,v (per-head 4x4) -> gin_T [1152][576] channel-major
__global__ __launch_bounds__(384) void k_qkv(const float* __restrict__ xa,
    const float* __restrict__ xin,
    const float* __restrict__ qw, const float* __restrict__ qb,
    const float* __restrict__ kw, const float* __restrict__ kb,
    const float* __restrict__ vw, const float* __restrict__ vb,
    float* __restrict__ ginT) {
  int s = blockIdx.x, t = threadIdx.x;
  int n = t >> 2, o = t & 3;
  __shared__ float xas[INNER], xms[INNER];
  xas[t] = xa[s * INNER + t];
  xms[t] = xin[s * (2 * INNER) + t];
  __syncthreads();
  const float* xah = xas + n * 4;
  const float* xmh = xms + n * 4;
  float q = qb[t], k = kb[t], v = vb[t];
  #pragma unroll
  for (int i = 0; i < 4; ++i) {
    float xq = xah[i], xm = xmh[i];
    q += xq * qw[n * 16 + o * 4 + i];
    k += xq * kw[n * 16 + o * 4 + i];
    v += xm * vw[n * 16 + o * 4 + i];
  }
  ginT[t * SEQ + s]                 = q;
  ginT[(INNER + t) * SEQ + s]       = k;
  ginT[(2 * INNER + t) * SEQ + s]   = v;
}

// 5) gates: thread = one token, both gates for head n; gin_T coalesced.
//    grid (NHEAD, 3), block 192
__global__ __launch_bounds__(192) void k_gates(const float* __restrict__ ginT,
    const float* __restrict__ igw, const float* __restrict__ igb,
    const float* __restrict__ fgw, const float* __restrict__ fgb,
    float* __restrict__ ig, float* __restrict__ logf) {
  int n = blockIdx.x, t = threadIdx.x;
  int s = blockIdx.y * 192 + t;
  __shared__ float wi[GIN], wf[GIN];
  for (int j = t; j < GIN; j += 192) { wi[j] = igw[n * GIN + j]; wf[j] = fgw[n * GIN + j]; }
  __syncthreads();
  float ai = igb[n], af = fgb[n];
  #pragma unroll 8
  for (int j = 0; j < GIN; ++j) {
    float gv = ginT[j * SEQ + s];
    ai += gv * wi[j];
    af += gv * wf[j];
  }
  ig[n * SEQ + s] = ai;
  float ls = (af >= 0.f) ? -log1pf(expf(-af)) : (af - log1pf(expf(af)));
  logf[n * SEQ + s] = ls;
}

// 6) per-head inclusive cumsum of logf -> lfc (wave scan, 9 chunks of 64)
__global__ __launch_bounds__(64) void k_scan(const float* __restrict__ logf,
    float* __restrict__ lfc) {
  int n = blockIdx.x, t = threadIdx.x;
  float carry = 0.f;
  for (int c = 0; c < SEQ / 64; ++c) {
    int s = c * 64 + t;
    float v = logf[n * SEQ + s];
    #pragma unroll
    for (int off = 1; off < 64; off <<= 1) {
      float u = __shfl_up(v, off);
      if (t >= off) v += u;
    }
    v += carry;
    lfc[n * SEQ + s] = v;
    carry = __shfl(v, 63);
  }
}

// 7) mLSTM core + per-head groupnorm.  Block per head, thread per query row.
//    logD[s,t]-maxD[s] = e[t] - pm[s],  e[t]=ig[t]-lfc[t], pm = prefix-max(e)
__global__ __launch_bounds__(576) void k_mlstm(const float* __restrict__ ginT,
    const float* __restrict__ ig_g, const float* __restrict__ lfc_g,
    const float* __restrict__ onw, float* __restrict__ hout) {
  int n = blockIdx.x, s = threadIdx.x;
  __shared__ float ks[SEQ][4], vs[SEQ][4], es[SEQ];
  __shared__ float bufA[SEQ], bufB[SEQ];
  #pragma unroll
  for (int i = 0; i < 4; ++i) {
    ks[s][i] = ginT[(INNER + n * 4 + i) * SEQ + s] * 0.5f;   // k / sqrt(DH)
    vs[s][i] = ginT[(2 * INNER + n * 4 + i) * SEQ + s];
  }
  float lfs = lfc_g[n * SEQ + s];
  float e = ig_g[n * SEQ + s] - lfs;
  es[s] = e;
  bufA[s] = e;
  float q0 = ginT[(n * 4 + 0) * SEQ + s];
  float q1 = ginT[(n * 4 + 1) * SEQ + s];
  float q2 = ginT[(n * 4 + 2) * SEQ + s];
  float q3 = ginT[(n * 4 + 3) * SEQ + s];
  __syncthreads();
  // prefix max over es
  float* src = bufA; float* dst = bufB;
  for (int off = 1; off < SEQ; off <<= 1) {
    float v = src[s];
    if (s >= off) v = fmaxf(v, src[s - off]);
    dst[s] = v;
    __syncthreads();
    float* tmp = src; src = dst; dst = tmp;
  }
  float pm = src[s];                    // max_{t<=s} e[t];  maxD = lfs + pm
  float csum = 0.f, h0 = 0.f, h1 = 0.f, h2 = 0.f, h3 = 0.f;
  for (int tt = 0; tt <= s; ++tt) {
    float d = __expf(es[tt] - pm);
    float c = (q0 * ks[tt][0] + q1 * ks[tt][1] + q2 * ks[tt][2] + q3 * ks[tt][3]) * d;
    csum += c;
    h0 += c * vs[tt][0]; h1 += c * vs[tt][1]; h2 += c * vs[tt][2]; h3 += c * vs[tt][3];
  }
  float norm = fmaxf(fabsf(csum), __expf(-(lfs + pm))) + 1e-6f;
  float r = 1.0f / norm;
  h0 *= r; h1 *= r; h2 *= r; h3 *= r;
  float mu = (h0 + h1 + h2 + h3) * 0.25f;
  float d0 = h0 - mu, d1 = h1 - mu, d2 = h2 - mu, d3 = h3 - mu;
  float var = (d0 * d0 + d1 * d1 + d2 * d2 + d3 * d3) * 0.25f;
  float inv = rsqrtf(var + 1e-5f);
  float* ho = hout + s * INNER + n * 4;
  ho[0] = d0 * inv * onw[n * 4];
  ho[1] = d1 * inv * onw[n * 4 + 1];
  ho[2] = d2 * inv * onw[n * 4 + 2];
  ho[3] = d3 * inv * onw[n * 4 + 3];
}

// 8) h2 = (h + skip*xa) * silu(z);  out = h2 @ down_w.T + down_b
__global__ __launch_bounds__(192) void k_down(const float* __restrict__ hmat,
    const float* __restrict__ xa, const float* __restrict__ xin,
    const float* __restrict__ skip, const float* __restrict__ dw,
    const float* __restrict__ db, float* __restrict__ out) {
  int s = blockIdx.x, t = threadIdx.x;
  __shared__ float h2[INNER];
  for (int c = t; c < INNER; c += 192) {
    float z = xin[s * (2 * INNER) + INNER + c];
    float sil = z / (1.0f + __expf(-z));
    h2[c] = (hmat[s * INNER + c] + skip[c] * xa[s * INNER + c]) * sil;
  }
  __syncthreads();
  const float* wr = dw + t * INNER;
  float acc = db[t];
  #pragma unroll 4
  for (int c = 0; c < INNER; ++c) acc += h2[c] * wr[c];
  out[s * DIM + t] = acc;
}

extern "C" void kernel_launch(void* const* d_in, const int* in_sizes, int n_in,
                              void* d_out, int out_size, void* d_ws, size_t ws_size,
                              hipStream_t stream) {
  const float* x      = (const float*)d_in[0];
  const float* ln_w   = (const float*)d_in[2];
  const float* ln_b   = (const float*)d_in[3];
  const float* up_w   = (const float*)d_in[4];
  const float* up_b   = (const float*)d_in[5];
  const float* q_w    = (const float*)d_in[8];
  const float* q_b    = (const float*)d_in[9];
  const float* k_w    = (const float*)d_in[10];
  const float* k_b    = (const float*)d_in[11];
  const float* v_w    = (const float*)d_in[12];
  const float* v_b    = (const float*)d_in[13];
  const float* conv_w = (const float*)d_in[14];
  const float* conv_b = (const float*)d_in[15];
  const float* ig_w   = (const float*)d_in[16];
  const float* ig_b   = (const float*)d_in[17];
  const float* fg_w   = (const float*)d_in[18];
  const float* fg_b   = (const float*)d_in[19];
  const float* onorm_w= (const float*)d_in[20];
  const float* skip   = (const float*)d_in[21];
  const float* down_w = (const float*)d_in[22];
  const float* down_b = (const float*)d_in[23];
  float* out = (float*)d_out;

  float* ws     = (float*)d_ws;
  float* xn     = ws;                       // 576*192
  float* xinner = xn + SEQ * DIM;           // 576*768
  float* xa     = xinner + SEQ * 2 * INNER; // 576*384
  float* ginT   = xa + SEQ * INNER;         // 1152*576 (channel-major)
  float* ig     = ginT + GIN * SEQ;         // 96*576
  float* logf   = ig + NHEAD * SEQ;         // 96*576
  float* lfc    = logf + NHEAD * SEQ;       // 96*576
  float* hbuf   = lfc + NHEAD * SEQ;        // 576*384

  k_ln   <<<SEQ, 64, 0, stream>>>(x, ln_w, ln_b, xn);
  k_up   <<<SEQ, 256, 0, stream>>>(xn, up_w, up_b, xinner);
  k_conv <<<SEQ, 384, 0, stream>>>(xinner, conv_w, conv_b, xa);
  k_qkv  <<<SEQ, 384, 0, stream>>>(xa, xinner, q_w, q_b, k_w, k_b, v_w, v_b, ginT);
  k_gates<<<dim3(NHEAD, 3), 192, 0, stream>>>(ginT, ig_w, ig_b, fg_w, fg_b, ig, logf);
  k_scan <<<NHEAD, 64, 0, stream>>>(logf, lfc);
  k_mlstm<<<NHEAD, SEQ, 0, stream>>>(ginT, ig, lfc, onorm_w, hbuf);
  k_down <<<SEQ, 192, 0, stream>>>(hbuf, xa, xinner, skip, down_w, down_b, out);
}

// Round 3
// 157.181 us; speedup vs baseline: 5.6596x; 1.2404x over previous
//
#include <hip/hip_runtime.h>
#include <math.h>

#define SEQ 576
#define DIM 192
#define INNER 384
#define NHEAD 96
#define HS 24
#define WSZ 24
#define GIN 1152

__device__ __forceinline__ float wave_reduce_sum(float v) {
  #pragma unroll
  for (int off = 32; off > 0; off >>= 1) v += __shfl_down(v, off);
  return __shfl(v, 0);
}

// 1) LayerNorm over DIM=192, one wave per row
__global__ __launch_bounds__(64) void k_ln(const float* __restrict__ x,
    const float* __restrict__ w, const float* __restrict__ b,
    float* __restrict__ xn) {
  int s = blockIdx.x, t = threadIdx.x;
  const float* xr = x + s * DIM;
  float a0 = xr[t], a1 = xr[t + 64], a2 = xr[t + 128];
  float mu = wave_reduce_sum(a0 + a1 + a2) * (1.0f / DIM);
  float d0 = a0 - mu, d1 = a1 - mu, d2 = a2 - mu;
  float var = wave_reduce_sum(d0 * d0 + d1 * d1 + d2 * d2) * (1.0f / DIM);
  float inv = rsqrtf(var + 1e-5f);
  float* o = xn + s * DIM;
  o[t]       = d0 * inv * w[t]       + b[t];
  o[t + 64]  = d1 * inv * w[t + 64]  + b[t + 64];
  o[t + 128] = d2 * inv * w[t + 128] + b[t + 128];
}

// 2) tiled GEMM: x_inner = xn @ up_w.T + up_b.  BM=64,BN=32,K=192.
#define UPA 68
#define UPB 36
__global__ __launch_bounds__(256) void k_up(const float* __restrict__ xn,
    const float* __restrict__ w, const float* __restrict__ b,
    float* __restrict__ out) {
  int m0 = blockIdx.x * 64, n0 = blockIdx.y * 32;
  __shared__ float As[DIM * UPA];   // [k][m]
  __shared__ float Bs[DIM * UPB];   // [k][o]
  int t = threadIdx.x;
  for (int idx = t; idx < 64 * DIM; idx += 256) {
    int r = idx / DIM, k = idx % DIM;
    As[k * UPA + r] = xn[(m0 + r) * DIM + k];
  }
  for (int idx = t; idx < 32 * DIM; idx += 256) {
    int r = idx / DIM, k = idx % DIM;
    Bs[k * UPB + r] = w[(n0 + r) * DIM + k];
  }
  __syncthreads();
  int gm = t >> 4;        // 0..15 -> tokens 4gm..+3
  int gn = t & 15;        // 0..15 -> outputs 2gn..+1
  float acc[4][2];
  #pragma unroll
  for (int i = 0; i < 4; ++i)
    #pragma unroll
    for (int j = 0; j < 2; ++j) acc[i][j] = b[n0 + 2 * gn + j];
  #pragma unroll 4
  for (int kk = 0; kk < DIM; ++kk) {
    float4 a = *(const float4*)&As[kk * UPA + 4 * gm];
    float2 bv = *(const float2*)&Bs[kk * UPB + 2 * gn];
    acc[0][0] += a.x * bv.x; acc[0][1] += a.x * bv.y;
    acc[1][0] += a.y * bv.x; acc[1][1] += a.y * bv.y;
    acc[2][0] += a.z * bv.x; acc[2][1] += a.z * bv.y;
    acc[3][0] += a.w * bv.x; acc[3][1] += a.w * bv.y;
  }
  #pragma unroll
  for (int i = 0; i < 4; ++i) {
    float2 v = make_float2(acc[i][0], acc[i][1]);
    *(float2*)&out[(m0 + 4 * gm + i) * (2 * INNER) + n0 + 2 * gn] = v;
  }
}

// 3) depthwise 3x3 conv + SiLU
__global__ __launch_bounds__(384) void k_conv(const float* __restrict__ xin,
    const float* __restrict__ cw, const float* __restrict__ cb,
    float* __restrict__ xa) {
  int s = blockIdx.x, c = threadIdx.x;
  int h = s / WSZ, w = s % WSZ;
  float acc = cb[c];
  #pragma unroll
  for (int kh = 0; kh < 3; ++kh) {
    int hh = h + kh - 1;
    if (hh < 0 || hh >= HS) continue;
    #pragma unroll
    for (int kw = 0; kw < 3; ++kw) {
      int ww = w + kw - 1;
      if (ww < 0 || ww >= WSZ) continue;
      acc += xin[(hh * WSZ + ww) * (2 * INNER) + c] * cw[c * 9 + kh * 3 + kw];
    }
  }
  float sig = 1.0f / (1.0f + __expf(-acc));
  xa[s * INNER + c] = acc * sig;
}

// 4) headwise q,k,v -> gin_T [1152][576]
__global__ __launch_bounds__(384) void k_qkv(const float* __restrict__ xa,
    const float* __restrict__ xin,
    const float* __restrict__ qw, const float* __restrict__ qb,
    const float* __restrict__ kw, const float* __restrict__ kb,
    const float* __restrict__ vw, const float* __restrict__ vb,
    float* __restrict__ ginT) {
  int s = blockIdx.x, t = threadIdx.x;
  int n = t >> 2, o = t & 3;
  __shared__ float xas[INNER], xms[INNER];
  xas[t] = xa[s * INNER + t];
  xms[t] = xin[s * (2 * INNER) + t];
  __syncthreads();
  const float* xah = xas + n * 4;
  const float* xmh = xms + n * 4;
  float q = qb[t], k = kb[t], v = vb[t];
  #pragma unroll
  for (int i = 0; i < 4; ++i) {
    float xq = xah[i], xm = xmh[i];
    q += xq * qw[n * 16 + o * 4 + i];
    k += xq * kw[n * 16 + o * 4 + i];
    v += xm * vw[n * 16 + o * 4 + i];
  }
  ginT[t * SEQ + s]                 = q;
  ginT[(INNER + t) * SEQ + s]       = k;
  ginT[(2 * INNER + t) * SEQ + s]   = v;
}

// 5) gates
__global__ __launch_bounds__(192) void k_gates(const float* __restrict__ ginT,
    const float* __restrict__ igw, const float* __restrict__ igb,
    const float* __restrict__ fgw, const float* __restrict__ fgb,
    float* __restrict__ ig, float* __restrict__ logf) {
  int n = blockIdx.x, t = threadIdx.x;
  int s = blockIdx.y * 192 + t;
  __shared__ float wi[GIN], wf[GIN];
  for (int j = t; j < GIN; j += 192) { wi[j] = igw[n * GIN + j]; wf[j] = fgw[n * GIN + j]; }
  __syncthreads();
  float ai = igb[n], af = fgb[n];
  #pragma unroll 8
  for (int j = 0; j < GIN; ++j) {
    float gv = ginT[j * SEQ + s];
    ai += gv * wi[j];
    af += gv * wf[j];
  }
  ig[n * SEQ + s] = ai;
  float ls = (af >= 0.f) ? -log1pf(expf(-af)) : (af - log1pf(expf(af)));
  logf[n * SEQ + s] = ls;
}

// 6) per-head inclusive cumsum of logf -> lfc
__global__ __launch_bounds__(64) void k_scan(const float* __restrict__ logf,
    float* __restrict__ lfc) {
  int n = blockIdx.x, t = threadIdx.x;
  float carry = 0.f;
  for (int c = 0; c < SEQ / 64; ++c) {
    int s = c * 64 + t;
    float v = logf[n * SEQ + s];
    #pragma unroll
    for (int off = 1; off < 64; off <<= 1) {
      float u = __shfl_up(v, off);
      if (t >= off) v += u;
    }
    v += carry;
    lfc[n * SEQ + s] = v;
    carry = __shfl(v, 63);
  }
}

// 7) mLSTM core + per-head groupnorm
__global__ __launch_bounds__(576) void k_mlstm(const float* __restrict__ ginT,
    const float* __restrict__ ig_g, const float* __restrict__ lfc_g,
    const float* __restrict__ onw, float* __restrict__ hout) {
  int n = blockIdx.x, s = threadIdx.x;
  __shared__ float ks[SEQ][4], vs[SEQ][4], es[SEQ];
  __shared__ float bufA[SEQ], bufB[SEQ];
  #pragma unroll
  for (int i = 0; i < 4; ++i) {
    ks[s][i] = ginT[(INNER + n * 4 + i) * SEQ + s] * 0.5f;
    vs[s][i] = ginT[(2 * INNER + n * 4 + i) * SEQ + s];
  }
  float lfs = lfc_g[n * SEQ + s];
  float e = ig_g[n * SEQ + s] - lfs;
  es[s] = e;
  bufA[s] = e;
  float q0 = ginT[(n * 4 + 0) * SEQ + s];
  float q1 = ginT[(n * 4 + 1) * SEQ + s];
  float q2 = ginT[(n * 4 + 2) * SEQ + s];
  float q3 = ginT[(n * 4 + 3) * SEQ + s];
  __syncthreads();
  float* src = bufA; float* dst = bufB;
  for (int off = 1; off < SEQ; off <<= 1) {
    float v = src[s];
    if (s >= off) v = fmaxf(v, src[s - off]);
    dst[s] = v;
    __syncthreads();
    float* tmp = src; src = dst; dst = tmp;
  }
  float pm = src[s];
  float csum = 0.f, h0 = 0.f, h1 = 0.f, h2 = 0.f, h3 = 0.f;
  for (int tt = 0; tt <= s; ++tt) {
    float d = __expf(es[tt] - pm);
    float c = (q0 * ks[tt][0] + q1 * ks[tt][1] + q2 * ks[tt][2] + q3 * ks[tt][3]) * d;
    csum += c;
    h0 += c * vs[tt][0]; h1 += c * vs[tt][1]; h2 += c * vs[tt][2]; h3 += c * vs[tt][3];
  }
  float norm = fmaxf(fabsf(csum), __expf(-(lfs + pm))) + 1e-6f;
  float r = 1.0f / norm;
  h0 *= r; h1 *= r; h2 *= r; h3 *= r;
  float mu = (h0 + h1 + h2 + h3) * 0.25f;
  float d0 = h0 - mu, d1 = h1 - mu, d2 = h2 - mu, d3 = h3 - mu;
  float var = (d0 * d0 + d1 * d1 + d2 * d2 + d3 * d3) * 0.25f;
  float inv = rsqrtf(var + 1e-5f);
  float* ho = hout + s * INNER + n * 4;
  ho[0] = d0 * inv * onw[n * 4];
  ho[1] = d1 * inv * onw[n * 4 + 1];
  ho[2] = d2 * inv * onw[n * 4 + 2];
  ho[3] = d3 * inv * onw[n * 4 + 3];
}

// 8) tiled GEMM, fused h2 epilogue-A: out = h2 @ down_w.T + down_b
#define DNA 20
#define DNB 36
__global__ __launch_bounds__(128) void k_down(const float* __restrict__ hmat,
    const float* __restrict__ xa, const float* __restrict__ xin,
    const float* __restrict__ skip, const float* __restrict__ dw,
    const float* __restrict__ db, float* __restrict__ out) {
  int m0 = blockIdx.x * 16, n0 = blockIdx.y * 32;
  __shared__ float As[INNER * DNA];   // [k][m]
  __shared__ float Bs[INNER * DNB];   // [k][o]
  int t = threadIdx.x;
  for (int idx = t; idx < 16 * INNER; idx += 128) {
    int r = idx / INNER, k = idx % INNER;
    int s = m0 + r;
    float z = xin[s * (2 * INNER) + INNER + k];
    float sil = z / (1.0f + __expf(-z));
    As[k * DNA + r] = (hmat[s * INNER + k] + skip[k] * xa[s * INNER + k]) * sil;
  }
  for (int idx = t; idx < 32 * INNER; idx += 128) {
    int r = idx / INNER, k = idx % INNER;
    Bs[k * DNB + r] = dw[(n0 + r) * INNER + k];
  }
  __syncthreads();
  int gm = t >> 4;        // 0..7  -> tokens 2gm..+1
  int gn = t & 15;        // 0..15 -> outputs 2gn..+1
  float acc[2][2];
  #pragma unroll
  for (int i = 0; i < 2; ++i)
    #pragma unroll
    for (int j = 0; j < 2; ++j) acc[i][j] = db[n0 + 2 * gn + j];
  #pragma unroll 4
  for (int kk = 0; kk < INNER; ++kk) {
    float2 a = *(const float2*)&As[kk * DNA + 2 * gm];
    float2 bv = *(const float2*)&Bs[kk * DNB + 2 * gn];
    acc[0][0] += a.x * bv.x; acc[0][1] += a.x * bv.y;
    acc[1][0] += a.y * bv.x; acc[1][1] += a.y * bv.y;
  }
  #pragma unroll
  for (int i = 0; i < 2; ++i) {
    float2 v = make_float2(acc[i][0], acc[i][1]);
    *(float2*)&out[(m0 + 2 * gm + i) * DIM + n0 + 2 * gn] = v;
  }
}

extern "C" void kernel_launch(void* const* d_in, const int* in_sizes, int n_in,
                              void* d_out, int out_size, void* d_ws, size_t ws_size,
                              hipStream_t stream) {
  const float* x      = (const float*)d_in[0];
  const float* ln_w   = (const float*)d_in[2];
  const float* ln_b   = (const float*)d_in[3];
  const float* up_w   = (const float*)d_in[4];
  const float* up_b   = (const float*)d_in[5];
  const float* q_w    = (const float*)d_in[8];
  const float* q_b    = (const float*)d_in[9];
  const float* k_w    = (const float*)d_in[10];
  const float* k_b    = (const float*)d_in[11];
  const float* v_w    = (const float*)d_in[12];
  const float* v_b    = (const float*)d_in[13];
  const float* conv_w = (const float*)d_in[14];
  const float* conv_b = (const float*)d_in[15];
  const float* ig_w   = (const float*)d_in[16];
  const float* ig_b   = (const float*)d_in[17];
  const float* fg_w   = (const float*)d_in[18];
  const float* fg_b   = (const float*)d_in[19];
  const float* onorm_w= (const float*)d_in[20];
  const float* skip   = (const float*)d_in[21];
  const float* down_w = (const float*)d_in[22];
  const float* down_b = (const float*)d_in[23];
  float* out = (float*)d_out;

  float* ws     = (float*)d_ws;
  float* xn     = ws;                       // 576*192
  float* xinner = xn + SEQ * DIM;           // 576*768
  float* xa     = xinner + SEQ * 2 * INNER; // 576*384
  float* ginT   = xa + SEQ * INNER;         // 1152*576
  float* ig     = ginT + GIN * SEQ;         // 96*576
  float* logf   = ig + NHEAD * SEQ;         // 96*576
  float* lfc    = logf + NHEAD * SEQ;       // 96*576
  float* hbuf   = lfc + NHEAD * SEQ;        // 576*384

  k_ln   <<<SEQ, 64, 0, stream>>>(x, ln_w, ln_b, xn);
  k_up   <<<dim3(9, 24), 256, 0, stream>>>(xn, up_w, up_b, xinner);
  k_conv <<<SEQ, 384, 0, stream>>>(xinner, conv_w, conv_b, xa);
  k_qkv  <<<SEQ, 384, 0, stream>>>(xa, xinner, q_w, q_b, k_w, k_b, v_w, v_b, ginT);
  k_gates<<<dim3(NHEAD, 3), 192, 0, stream>>>(ginT, ig_w, ig_b, fg_w, fg_b, ig, logf);
  k_scan <<<NHEAD, 64, 0, stream>>>(logf, lfc);
  k_mlstm<<<NHEAD, SEQ, 0, stream>>>(ginT, ig, lfc, onorm_w, hbuf);
  k_down <<<dim3(36, 6), 128, 0, stream>>>(hbuf, xa, xinner, skip, down_w, down_b, out);
}

// Round 4
// 142.510 us; speedup vs baseline: 6.2422x; 1.1029x over previous
//
#include <hip/hip_runtime.h>
#include <math.h>

#define SEQ 576
#define DIM 192
#define INNER 384
#define NHEAD 96
#define HS 24
#define WSZ 24
#define GIN 1152

__device__ __forceinline__ float wave_reduce_sum(float v) {
  #pragma unroll
  for (int off = 32; off > 0; off >>= 1) v += __shfl_down(v, off);
  return __shfl(v, 0);
}

// 1) LayerNorm over DIM=192, one wave per row
__global__ __launch_bounds__(64) void k_ln(const float* __restrict__ x,
    const float* __restrict__ w, const float* __restrict__ b,
    float* __restrict__ xn) {
  int s = blockIdx.x, t = threadIdx.x;
  const float* xr = x + s * DIM;
  float a0 = xr[t], a1 = xr[t + 64], a2 = xr[t + 128];
  float mu = wave_reduce_sum(a0 + a1 + a2) * (1.0f / DIM);
  float d0 = a0 - mu, d1 = a1 - mu, d2 = a2 - mu;
  float var = wave_reduce_sum(d0 * d0 + d1 * d1 + d2 * d2) * (1.0f / DIM);
  float inv = rsqrtf(var + 1e-5f);
  float* o = xn + s * DIM;
  o[t]       = d0 * inv * w[t]       + b[t];
  o[t + 64]  = d1 * inv * w[t + 64]  + b[t + 64];
  o[t + 128] = d2 * inv * w[t + 128] + b[t + 128];
}

// 2) tiled GEMM: x_inner = xn @ up_w.T + up_b.  BM=64,BN=32,K=192.
#define UPA 68
#define UPB 36
__global__ __launch_bounds__(256) void k_up(const float* __restrict__ xn,
    const float* __restrict__ w, const float* __restrict__ b,
    float* __restrict__ out) {
  int m0 = blockIdx.x * 64, n0 = blockIdx.y * 32;
  __shared__ float As[DIM * UPA];   // [k][m]
  __shared__ float Bs[DIM * UPB];   // [k][o]
  int t = threadIdx.x;
  for (int idx = t; idx < 64 * DIM; idx += 256) {
    int r = idx / DIM, k = idx % DIM;
    As[k * UPA + r] = xn[(m0 + r) * DIM + k];
  }
  for (int idx = t; idx < 32 * DIM; idx += 256) {
    int r = idx / DIM, k = idx % DIM;
    Bs[k * UPB + r] = w[(n0 + r) * DIM + k];
  }
  __syncthreads();
  int gm = t >> 4;        // 0..15 -> tokens 4gm..+3
  int gn = t & 15;        // 0..15 -> outputs 2gn..+1
  float acc[4][2];
  #pragma unroll
  for (int i = 0; i < 4; ++i)
    #pragma unroll
    for (int j = 0; j < 2; ++j) acc[i][j] = b[n0 + 2 * gn + j];
  #pragma unroll 4
  for (int kk = 0; kk < DIM; ++kk) {
    float4 a = *(const float4*)&As[kk * UPA + 4 * gm];
    float2 bv = *(const float2*)&Bs[kk * UPB + 2 * gn];
    acc[0][0] += a.x * bv.x; acc[0][1] += a.x * bv.y;
    acc[1][0] += a.y * bv.x; acc[1][1] += a.y * bv.y;
    acc[2][0] += a.z * bv.x; acc[2][1] += a.z * bv.y;
    acc[3][0] += a.w * bv.x; acc[3][1] += a.w * bv.y;
  }
  #pragma unroll
  for (int i = 0; i < 4; ++i) {
    float2 v = make_float2(acc[i][0], acc[i][1]);
    *(float2*)&out[(m0 + 4 * gm + i) * (2 * INNER) + n0 + 2 * gn] = v;
  }
}

// 3) depthwise 3x3 conv + SiLU
__global__ __launch_bounds__(384) void k_conv(const float* __restrict__ xin,
    const float* __restrict__ cw, const float* __restrict__ cb,
    float* __restrict__ xa) {
  int s = blockIdx.x, c = threadIdx.x;
  int h = s / WSZ, w = s % WSZ;
  float acc = cb[c];
  #pragma unroll
  for (int kh = 0; kh < 3; ++kh) {
    int hh = h + kh - 1;
    if (hh < 0 || hh >= HS) continue;
    #pragma unroll
    for (int kw = 0; kw < 3; ++kw) {
      int ww = w + kw - 1;
      if (ww < 0 || ww >= WSZ) continue;
      acc += xin[(hh * WSZ + ww) * (2 * INNER) + c] * cw[c * 9 + kh * 3 + kw];
    }
  }
  float sig = 1.0f / (1.0f + __expf(-acc));
  xa[s * INNER + c] = acc * sig;
}

// 4) headwise q,k,v -> gin_T [1152][576]
__global__ __launch_bounds__(384) void k_qkv(const float* __restrict__ xa,
    const float* __restrict__ xin,
    const float* __restrict__ qw, const float* __restrict__ qb,
    const float* __restrict__ kw, const float* __restrict__ kb,
    const float* __restrict__ vw, const float* __restrict__ vb,
    float* __restrict__ ginT) {
  int s = blockIdx.x, t = threadIdx.x;
  int n = t >> 2, o = t & 3;
  __shared__ float xas[INNER], xms[INNER];
  xas[t] = xa[s * INNER + t];
  xms[t] = xin[s * (2 * INNER) + t];
  __syncthreads();
  const float* xah = xas + n * 4;
  const float* xmh = xms + n * 4;
  float q = qb[t], k = kb[t], v = vb[t];
  #pragma unroll
  for (int i = 0; i < 4; ++i) {
    float xq = xah[i], xm = xmh[i];
    q += xq * qw[n * 16 + o * 4 + i];
    k += xq * kw[n * 16 + o * 4 + i];
    v += xm * vw[n * 16 + o * 4 + i];
  }
  ginT[t * SEQ + s]                 = q;
  ginT[(INNER + t) * SEQ + s]       = k;
  ginT[(2 * INNER + t) * SEQ + s]   = v;
}

// 5) gate GEMM: C[192,576] = W[192,1152] @ ginT[1152,576], K-split into 4
//    slices -> deterministic partial buffers pig/pfg[4][96][576].
//    rows 0..95 = ig heads (igw), rows 96..191 = fg heads (fgw).
#define GBM 16
#define GBN 64
#define GBK 32
#define GKS 4
#define GSL (GIN / GKS)   // 288
#define WPAD 20
__global__ __launch_bounds__(128) void k_gates(const float* __restrict__ ginT,
    const float* __restrict__ igw, const float* __restrict__ fgw,
    float* __restrict__ pig, float* __restrict__ pfg) {
  int m0 = blockIdx.x * GBM, s0 = blockIdx.y * GBN, ks = blockIdx.z;
  int k0 = ks * GSL;
  __shared__ float Ws[GBK * WPAD];  // [kk][r]
  __shared__ float Gs[GBK * GBN];   // [kk][ss]
  int t = threadIdx.x;
  const float* wbase = (m0 < NHEAD) ? (igw + m0 * GIN) : (fgw + (m0 - NHEAD) * GIN);
  int gm = t >> 4, gn = t & 15;     // gm 0..7 (m-pairs), gn 0..15 (n-quads)
  float acc[2][4] = {{0.f,0.f,0.f,0.f},{0.f,0.f,0.f,0.f}};
  for (int kc = 0; kc < GSL; kc += GBK) {
    __syncthreads();
    for (int idx = t; idx < GBM * GBK; idx += 128) {
      int r = idx >> 5, kk = idx & 31;
      Ws[kk * WPAD + r] = wbase[r * GIN + k0 + kc + kk];
    }
    for (int idx = t; idx < GBK * GBN; idx += 128) {
      int kk = idx >> 6, ss = idx & 63;
      Gs[kk * GBN + ss] = ginT[(k0 + kc + kk) * SEQ + s0 + ss];
    }
    __syncthreads();
    #pragma unroll 8
    for (int kk = 0; kk < GBK; ++kk) {
      float2 wv = *(const float2*)&Ws[kk * WPAD + 2 * gm];
      float4 gv = *(const float4*)&Gs[kk * GBN + 4 * gn];
      acc[0][0] += wv.x * gv.x; acc[0][1] += wv.x * gv.y;
      acc[0][2] += wv.x * gv.z; acc[0][3] += wv.x * gv.w;
      acc[1][0] += wv.y * gv.x; acc[1][1] += wv.y * gv.y;
      acc[1][2] += wv.y * gv.z; acc[1][3] += wv.y * gv.w;
    }
  }
  #pragma unroll
  for (int i = 0; i < 2; ++i) {
    int m = m0 + 2 * gm + i;
    float* dst = (m < NHEAD) ? (pig + ks * NHEAD * SEQ + m * SEQ)
                             : (pfg + ks * NHEAD * SEQ + (m - NHEAD) * SEQ);
    *(float4*)&dst[s0 + 4 * gn] = make_float4(acc[i][0], acc[i][1], acc[i][2], acc[i][3]);
  }
}

// 6) combine gate partials + biases; log-sigmoid; per-head cumsum -> ig, lfc
__global__ __launch_bounds__(64) void k_scan(const float* __restrict__ pig,
    const float* __restrict__ pfg, const float* __restrict__ igb,
    const float* __restrict__ fgb, float* __restrict__ ig,
    float* __restrict__ lfc) {
  int n = blockIdx.x, t = threadIdx.x;
  float bi = igb[n], bf = fgb[n];
  float carry = 0.f;
  const int HS4 = NHEAD * SEQ;
  for (int c = 0; c < SEQ / 64; ++c) {
    int s = c * 64 + t;
    int off = n * SEQ + s;
    float ai = bi + pig[off] + pig[HS4 + off] + pig[2 * HS4 + off] + pig[3 * HS4 + off];
    float af = bf + pfg[off] + pfg[HS4 + off] + pfg[2 * HS4 + off] + pfg[3 * HS4 + off];
    ig[off] = ai;
    float v = (af >= 0.f) ? -log1pf(expf(-af)) : (af - log1pf(expf(af)));
    #pragma unroll
    for (int offx = 1; offx < 64; offx <<= 1) {
      float u = __shfl_up(v, offx);
      if (t >= offx) v += u;
    }
    v += carry;
    lfc[off] = v;
    carry = __shfl(v, 63);
  }
}

// 7) mLSTM core + per-head groupnorm
__global__ __launch_bounds__(576) void k_mlstm(const float* __restrict__ ginT,
    const float* __restrict__ ig_g, const float* __restrict__ lfc_g,
    const float* __restrict__ onw, float* __restrict__ hout) {
  int n = blockIdx.x, s = threadIdx.x;
  __shared__ float ks[SEQ][4], vs[SEQ][4], es[SEQ];
  __shared__ float bufA[SEQ], bufB[SEQ];
  #pragma unroll
  for (int i = 0; i < 4; ++i) {
    ks[s][i] = ginT[(INNER + n * 4 + i) * SEQ + s] * 0.5f;
    vs[s][i] = ginT[(2 * INNER + n * 4 + i) * SEQ + s];
  }
  float lfs = lfc_g[n * SEQ + s];
  float e = ig_g[n * SEQ + s] - lfs;
  es[s] = e;
  bufA[s] = e;
  float q0 = ginT[(n * 4 + 0) * SEQ + s];
  float q1 = ginT[(n * 4 + 1) * SEQ + s];
  float q2 = ginT[(n * 4 + 2) * SEQ + s];
  float q3 = ginT[(n * 4 + 3) * SEQ + s];
  __syncthreads();
  float* src = bufA; float* dst = bufB;
  for (int off = 1; off < SEQ; off <<= 1) {
    float v = src[s];
    if (s >= off) v = fmaxf(v, src[s - off]);
    dst[s] = v;
    __syncthreads();
    float* tmp = src; src = dst; dst = tmp;
  }
  float pm = src[s];
  float csum = 0.f, h0 = 0.f, h1 = 0.f, h2 = 0.f, h3 = 0.f;
  for (int tt = 0; tt <= s; ++tt) {
    float d = __expf(es[tt] - pm);
    float c = (q0 * ks[tt][0] + q1 * ks[tt][1] + q2 * ks[tt][2] + q3 * ks[tt][3]) * d;
    csum += c;
    h0 += c * vs[tt][0]; h1 += c * vs[tt][1]; h2 += c * vs[tt][2]; h3 += c * vs[tt][3];
  }
  float norm = fmaxf(fabsf(csum), __expf(-(lfs + pm))) + 1e-6f;
  float r = 1.0f / norm;
  h0 *= r; h1 *= r; h2 *= r; h3 *= r;
  float mu = (h0 + h1 + h2 + h3) * 0.25f;
  float d0 = h0 - mu, d1 = h1 - mu, d2 = h2 - mu, d3 = h3 - mu;
  float var = (d0 * d0 + d1 * d1 + d2 * d2 + d3 * d3) * 0.25f;
  float inv = rsqrtf(var + 1e-5f);
  float* ho = hout + s * INNER + n * 4;
  ho[0] = d0 * inv * onw[n * 4];
  ho[1] = d1 * inv * onw[n * 4 + 1];
  ho[2] = d2 * inv * onw[n * 4 + 2];
  ho[3] = d3 * inv * onw[n * 4 + 3];
}

// 8) tiled GEMM, fused h2 epilogue-A: out = h2 @ down_w.T + down_b
#define DNA 20
#define DNB 36
__global__ __launch_bounds__(128) void k_down(const float* __restrict__ hmat,
    const float* __restrict__ xa, const float* __restrict__ xin,
    const float* __restrict__ skip, const float* __restrict__ dw,
    const float* __restrict__ db, float* __restrict__ out) {
  int m0 = blockIdx.x * 16, n0 = blockIdx.y * 32;
  __shared__ float As[INNER * DNA];   // [k][m]
  __shared__ float Bs[INNER * DNB];   // [k][o]
  int t = threadIdx.x;
  for (int idx = t; idx < 16 * INNER; idx += 128) {
    int r = idx / INNER, k = idx % INNER;
    int s = m0 + r;
    float z = xin[s * (2 * INNER) + INNER + k];
    float sil = z / (1.0f + __expf(-z));
    As[k * DNA + r] = (hmat[s * INNER + k] + skip[k] * xa[s * INNER + k]) * sil;
  }
  for (int idx = t; idx < 32 * INNER; idx += 128) {
    int r = idx / INNER, k = idx % INNER;
    Bs[k * DNB + r] = dw[(n0 + r) * INNER + k];
  }
  __syncthreads();
  int gm = t >> 4;        // 0..7  -> tokens 2gm..+1
  int gn = t & 15;        // 0..15 -> outputs 2gn..+1
  float acc[2][2];
  #pragma unroll
  for (int i = 0; i < 2; ++i)
    #pragma unroll
    for (int j = 0; j < 2; ++j) acc[i][j] = db[n0 + 2 * gn + j];
  #pragma unroll 4
  for (int kk = 0; kk < INNER; ++kk) {
    float2 a = *(const float2*)&As[kk * DNA + 2 * gm];
    float2 bv = *(const float2*)&Bs[kk * DNB + 2 * gn];
    acc[0][0] += a.x * bv.x; acc[0][1] += a.x * bv.y;
    acc[1][0] += a.y * bv.x; acc[1][1] += a.y * bv.y;
  }
  #pragma unroll
  for (int i = 0; i < 2; ++i) {
    float2 v = make_float2(acc[i][0], acc[i][1]);
    *(float2*)&out[(m0 + 2 * gm + i) * DIM + n0 + 2 * gn] = v;
  }
}

extern "C" void kernel_launch(void* const* d_in, const int* in_sizes, int n_in,
                              void* d_out, int out_size, void* d_ws, size_t ws_size,
                              hipStream_t stream) {
  const float* x      = (const float*)d_in[0];
  const float* ln_w   = (const float*)d_in[2];
  const float* ln_b   = (const float*)d_in[3];
  const float* up_w   = (const float*)d_in[4];
  const float* up_b   = (const float*)d_in[5];
  const float* q_w    = (const float*)d_in[8];
  const float* q_b    = (const float*)d_in[9];
  const float* k_w    = (const float*)d_in[10];
  const float* k_b    = (const float*)d_in[11];
  const float* v_w    = (const float*)d_in[12];
  const float* v_b    = (const float*)d_in[13];
  const float* conv_w = (const float*)d_in[14];
  const float* conv_b = (const float*)d_in[15];
  const float* ig_w   = (const float*)d_in[16];
  const float* ig_b   = (const float*)d_in[17];
  const float* fg_w   = (const float*)d_in[18];
  const float* fg_b   = (const float*)d_in[19];
  const float* onorm_w= (const float*)d_in[20];
  const float* skip   = (const float*)d_in[21];
  const float* down_w = (const float*)d_in[22];
  const float* down_b = (const float*)d_in[23];
  float* out = (float*)d_out;

  float* ws     = (float*)d_ws;
  float* xn     = ws;                       // 576*192
  float* xinner = xn + SEQ * DIM;           // 576*768
  float* xa     = xinner + SEQ * 2 * INNER; // 576*384
  float* ginT   = xa + SEQ * INNER;         // 1152*576
  float* ig     = ginT + GIN * SEQ;         // 96*576
  float* lfc    = ig + NHEAD * SEQ;         // 96*576
  float* pig    = lfc + NHEAD * SEQ;        // 4*96*576
  float* pfg    = pig + GKS * NHEAD * SEQ;  // 4*96*576
  float* hbuf   = pfg + GKS * NHEAD * SEQ;  // 576*384

  k_ln   <<<SEQ, 64, 0, stream>>>(x, ln_w, ln_b, xn);
  k_up   <<<dim3(9, 24), 256, 0, stream>>>(xn, up_w, up_b, xinner);
  k_conv <<<SEQ, 384, 0, stream>>>(xinner, conv_w, conv_b, xa);
  k_qkv  <<<SEQ, 384, 0, stream>>>(xa, xinner, q_w, q_b, k_w, k_b, v_w, v_b, ginT);
  k_gates<<<dim3(12, 9, GKS), 128, 0, stream>>>(ginT, ig_w, fg_w, pig, pfg);
  k_scan <<<NHEAD, 64, 0, stream>>>(pig, pfg, ig_b, fg_b, ig, lfc);
  k_mlstm<<<NHEAD, SEQ, 0, stream>>>(ginT, ig, lfc, onorm_w, hbuf);
  k_down <<<dim3(36, 6), 128, 0, stream>>>(hbuf, xa, xinner, skip, down_w, down_b, out);
}